// Round 10
// baseline (377.077 us; speedup 1.0000x reference)
//
#include <hip/hip_runtime.h>
#include <hip/hip_bf16.h>

// MSDNet on MI355X. Only scale 2's chain matters (scales 0/1 dead), and
// final_logits == logits at depth 3.
// conv_mfma v6 = r8's per-wave W-DMA pipeline (proven correct) + r9's
// q-streamed A (proven fast):
//   2-wave blocks, wave tile 128px x 64co (acc[8][4]); A chunk (32 cin) in
//   s_in 14.4KB restaged per q; W per-wave triple-buffered via
//   global_load_lds, counted vmcnt(4), ZERO step barriers (only 2 raw
//   barriers per q boundary, no vmcnt drain). 4 blocks/CU.

typedef unsigned int uint;
typedef unsigned short u16;
typedef __bf16 bf16x8 __attribute__((ext_vector_type(8)));
typedef short short8 __attribute__((ext_vector_type(8)));
typedef unsigned short ushort8 __attribute__((ext_vector_type(8)));
typedef float f32x4 __attribute__((ext_vector_type(4)));

#define NB   16
#define CCH  128
#define NCLS 100
#define HW   12544      // 112*112
#define NTILE 98        // 14 h-tiles x 7 w-tiles per image

__device__ __forceinline__ u16 f2bf(float f) {
    uint u = __float_as_uint(f);
    return (u16)((u + 0x7fffu + ((u >> 16) & 1u)) >> 16);
}

__device__ __forceinline__ void gload16(const u16* g, u16* l) {
    __builtin_amdgcn_global_load_lds(
        (const __attribute__((address_space(1))) uint*)g,
        (__attribute__((address_space(3))) uint*)l, 16, 0, 0);
}

// ---------------- weight transpose+convert: block_w[d][2][co][ci][kh][kw] f32
// -> wb[d][tap][co][ci] bf16 ----------------
__global__ __launch_bounds__(256) void convert_w(
    const float* __restrict__ bw, u16* __restrict__ wb)
{
    int idx = blockIdx.x * 256 + threadIdx.x;        // 4*9*128*128
    if (idx >= 4 * 9 * 16384) return;
    int d = idx / 147456, r = idx % 147456;
    int t = r / 16384, r2 = r & 16383;
    int co = r2 >> 7, ci = r2 & 127;
    float v = bw[((size_t)(d * 3 + 2) * 16384 + co * 128 + ci) * 9 + t];
    wb[idx] = f2bf(v);
}

// ---------------- init conv: cin=3, fp32 VALU, NCHW fp32 in -> NHWC bf16 out ----------------
__global__ __launch_bounds__(256) void conv_init(
    const float* __restrict__ in,    // [16][3][112][112]
    const float* __restrict__ wgt,   // [128][3][3][3]
    const float* __restrict__ bias,  // [128]
    u16* __restrict__ outp)          // [16][12544][128] bf16
{
    const int tile = blockIdx.x;          // 0..48 (16x16 tiles)
    const int cg   = blockIdx.y;          // 0..3  (32 couts)
    const int n    = blockIdx.z;
    const int h0 = (tile / 7) * 16, w0 = (tile % 7) * 16;
    const int tid = threadIdx.x;
    const int sid = tid & 63, wv = tid >> 6;
    const int tx = sid & 7, ty = sid >> 3;

    __shared__ float s_in[3][18][18];
    __shared__ float s_w[3][9][32];

    float acc[2][2][8];
    #pragma unroll
    for (int a = 0; a < 2; a++)
        #pragma unroll
        for (int b = 0; b < 2; b++)
            #pragma unroll
            for (int c = 0; c < 8; c++) acc[a][b][c] = 0.f;

    const float* in_n = in + (size_t)n * 3 * HW;
    const int cbase = cg * 32;

    for (int e = tid; e < 3 * 324; e += 256) {
        int ck = e / 324, p = e % 324;
        int y = p / 18, x = p % 18;
        int gh = h0 + y - 1, gw = w0 + x - 1;
        float v = 0.f;
        if ((unsigned)gh < 112u && (unsigned)gw < 112u)
            v = in_n[(size_t)ck * HW + gh * 112 + gw];
        s_in[ck][y][x] = v;
    }
    for (int e = tid; e < 3 * 9 * 32; e += 256) {
        int co = e / 27, r = e % 27;
        int ck = r / 9, kidx = r % 9;
        s_w[ck][kidx][co] = wgt[((size_t)(cbase + co) * 3 + ck) * 9 + kidx];
    }
    __syncthreads();

    #pragma unroll
    for (int ck = 0; ck < 3; ck++) {
        float rowv[4][4];
        #pragma unroll
        for (int r = 0; r < 4; r++) {
            float2 a  = *(const float2*)&s_in[ck][ty * 2 + r][tx * 2];
            float2 b2 = *(const float2*)&s_in[ck][ty * 2 + r][tx * 2 + 2];
            rowv[r][0] = a.x; rowv[r][1] = a.y;
            rowv[r][2] = b2.x; rowv[r][3] = b2.y;
        }
        #pragma unroll
        for (int kh = 0; kh < 3; kh++)
            #pragma unroll
            for (int kw = 0; kw < 3; kw++) {
                float i00 = rowv[kh][kw],     i01 = rowv[kh][kw + 1];
                float i10 = rowv[kh + 1][kw], i11 = rowv[kh + 1][kw + 1];
                const float* wp = &s_w[ck][kh * 3 + kw][wv * 8];
                #pragma unroll
                for (int co = 0; co < 8; co++) {
                    float wval = wp[co];
                    acc[0][0][co] += i00 * wval;
                    acc[0][1][co] += i01 * wval;
                    acc[1][0][co] += i10 * wval;
                    acc[1][1][co] += i11 * wval;
                }
            }
    }

    float bv[8];
    #pragma unroll
    for (int co = 0; co < 8; co++) bv[co] = bias[cbase + wv * 8 + co];
    #pragma unroll
    for (int dy = 0; dy < 2; dy++)
        #pragma unroll
        for (int dx = 0; dx < 2; dx++) {
            ushort8 pk;
            #pragma unroll
            for (int co = 0; co < 8; co++)
                pk[co] = f2bf(acc[dy][dx][co] + bv[co]);   // no relu on init
            int h = h0 + ty * 2 + dy, w = w0 + tx * 2 + dx;
            *(ushort8*)(outp + (((size_t)n * HW + h * 112 + w) << 7) + cbase + wv * 8) = pk;
        }
}

// ---------------- MFMA implicit-GEMM 3x3 conv, 128->128, bf16 NHWC ----------------
// Block: 128 thr (2 waves), tile M=128 px (8 rows x 16 cols), N=128 couts.
// Wave w owns couts w*64..+63 for ALL 128 px: acc[8][4], 8 A + 4 B ds_reads,
// 32 MFMA per step. Loop: q outer (4 cin chunks), taps inner (9).
// A: s_in[180][40] one q-chunk, restaged per q (reg-staged, 2 raw barriers).
// W: per-wave gload16 -> s_w[w][3 bufs][2048], vmcnt(4), no step barriers.
#define AS 40           // s_in elems per px (32 + 8 pad) -> 80B stride

template<bool STORE>
__global__ __launch_bounds__(128, 2) void conv_mfma(
    const u16* __restrict__ in,     // [16][12544][128] bf16
    const u16* __restrict__ wb,     // [9][128][128] bf16 (tap, cout, cin)
    const float* __restrict__ bias, // [128]
    u16* __restrict__ outp,         // [16][12544][128] bf16 (unused if !STORE)
    float* __restrict__ partial)    // [16][98][128] f32 per-block pooled sums
{
    __shared__ u16 s_in[180 * AS];          // 14,400 B (one q-chunk + halo)
    __shared__ u16 s_w[2][3][2048];         // 24,576 B [wave][buf][64co x 32ci]
    float* s_pool = (float*)s_in;           // overlay (after K-loop)

    const int tile = blockIdx.x;            // 0..97
    const int n    = blockIdx.y;
    const int h0 = (tile / 7) * 8, w0 = (tile % 7) * 16;
    const int tid = threadIdx.x, lane = tid & 63;
    const int w = tid >> 6;                 // wave id = cout half
    const int l15 = lane & 15, l4 = lane >> 4;

    const u16* in_n = in + ((size_t)n * HW << 7);

    // W DMA (r8-proven): lane l -> LDS granule (co' = l>>2, gpos = l&3);
    // source granule chunk = gpos ^ ((co'>>1)&3) = (l&3)^((l>>3)&3)
    const int co_g = w * 64 + (lane >> 2);
    const int c2e  = ((lane & 3) ^ ((lane >> 3) & 3)) << 3;
    const u16* wsrc0 = wb + co_g * 128 + c2e;   // + tap*16384 + q*32 + i*2048
    u16* ldsw = &s_w[w][0][0];                  // + buf*2048 + i*512

    // ---- prologue: issue W batch(0)=tap0,q0 -> buf0 ; batch(1)=tap1,q0 -> buf1
    #pragma unroll
    for (int i = 0; i < 4; ++i) gload16(wsrc0 + (i << 11), ldsw + (i << 9));
    #pragma unroll
    for (int i = 0; i < 4; ++i)
        gload16(wsrc0 + 16384 + (i << 11), ldsw + 2048 + (i << 9));

    // ---- stage A(q=0): 180 px x 32 cin (halo, zero-padded), reg-staged ----
    for (int g = tid; g < 720; g += 128) {
        int px = g >> 2, c8 = (g & 3) << 3;
        int hh = px / 18, ww2 = px - hh * 18;
        int gh = h0 + hh - 1, gw = w0 + ww2 - 1;
        uint4 v = make_uint4(0, 0, 0, 0);
        if ((unsigned)gh < 112u && (unsigned)gw < 112u)
            v = *(const uint4*)(in_n + ((size_t)(gh * 112 + gw) << 7) + c8);
        *(uint4*)(s_in + px * AS + c8) = v;
    }

    f32x4 acc[8][4];
    #pragma unroll
    for (int i = 0; i < 8; ++i)
        #pragma unroll
        for (int j = 0; j < 4; ++j)
            #pragma unroll
            for (int e = 0; e < 4; ++e) acc[i][j][e] = 0.f;

    // read bases
    const int pB0 = l15 * 32 + ((l4 ^ ((l15 >> 1) & 3)) << 3);  // within wave buf

    __syncthreads();    // A(0) staged; drains vmcnt once (W(0),W(1) land)

    for (int q = 0; q < 4; ++q) {
        #pragma unroll
        for (int t = 0; t < 9; ++t) {
            // W(step) guaranteed in LDS: <=4 outstanding leaves only newest batch
            asm volatile("s_waitcnt vmcnt(4)" ::: "memory");

            const int kh = t / 3, kw = t - kh * 3;
            bf16x8 a[8], b[4];
            #pragma unroll
            for (int fi = 0; fi < 8; ++fi) {
                const u16* p = s_in + ((fi + kh) * 18 + kw + l15) * AS + (l4 << 3);
                a[fi] = __builtin_bit_cast(bf16x8, *(const short8*)p);
            }
            const u16* rb = &s_w[w][t % 3][0] + pB0;
            #pragma unroll
            for (int nj = 0; nj < 4; ++nj)
                b[nj] = __builtin_bit_cast(bf16x8, *(const short8*)(rb + (nj << 9)));

            // q-boundary: issue A(q+1) loads BEFORE the W batch (keeps the
            // oldest-first vmcnt(4) invariant exact)
            uint4 av[6];
            if (t == 8 && q < 3) {
                #pragma unroll
                for (int r = 0; r < 6; ++r) {
                    int g = tid + (r << 7);
                    int px = g >> 2, c8 = (g & 3) << 3;
                    int hh = px / 18, ww2 = px - hh * 18;
                    int gh = h0 + hh - 1, gw = w0 + ww2 - 1;
                    uint4 v = make_uint4(0, 0, 0, 0);
                    if (g < 720 && (unsigned)gh < 112u && (unsigned)gw < 112u)
                        v = *(const uint4*)(in_n + ((size_t)(gh * 112 + gw) << 7)
                                            + ((q + 1) << 5) + c8);
                    av[r] = v;
                }
            }

            // issue W batch(s+2) into buf (t+2)%3 (skip at very end)
            if (!(q == 3 && t >= 7)) {
                const int tn = (t + 2) % 9, qn = q + (t >= 7 ? 1 : 0);
                const u16* src = wsrc0 + tn * 16384 + (qn << 5);
                u16* dst = ldsw + ((t + 2) % 3) * 2048;
                #pragma unroll
                for (int i = 0; i < 4; ++i)
                    gload16(src + (i << 11), dst + (i << 9));
            }

            #pragma unroll
            for (int fi = 0; fi < 8; ++fi)
                #pragma unroll
                for (int nj = 0; nj < 4; ++nj)
                    acc[fi][nj] = __builtin_amdgcn_mfma_f32_16x16x32_bf16(
                        a[fi], b[nj], acc[fi][nj], 0, 0, 0);

            if (t == 8 && q < 3) {
                // raw barriers: NO vmcnt drain, W batches stay in flight
                __builtin_amdgcn_s_barrier();       // all waves done reading q
                #pragma unroll
                for (int r = 0; r < 6; ++r) {
                    int g = tid + (r << 7);
                    if (g < 720) {
                        int px = g >> 2, c8 = (g & 3) << 3;
                        *(uint4*)(s_in + px * AS + c8) = av[r];
                    }
                }
                asm volatile("s_waitcnt lgkmcnt(0)" ::: "memory");
                __builtin_amdgcn_s_barrier();       // new A visible
                __builtin_amdgcn_sched_barrier(0);
            }
        }
    }

    // ---- epilogue: bias + relu, optional stores, fused pooling ----
    // D layout: col = l15 (cout), row = l4*4 + j (pixel col in the fi-row)
    float bv[4], ps[4];
    #pragma unroll
    for (int nj = 0; nj < 4; ++nj) { bv[nj] = bias[w * 64 + nj * 16 + l15]; ps[nj] = 0.f; }
    u16* out_n = outp + ((size_t)n * HW << 7);
    #pragma unroll
    for (int fi = 0; fi < 8; ++fi) {
        int h = h0 + fi;
        #pragma unroll
        for (int j = 0; j < 4; ++j) {
            int wpx = w0 + (l4 << 2) + j;
            u16* pr = out_n + ((size_t)(h * 112 + wpx) << 7);
            #pragma unroll
            for (int nj = 0; nj < 4; ++nj) {
                float v = fmaxf(acc[fi][nj][j] + bv[nj], 0.f);
                ps[nj] += v;
                if (STORE) pr[w * 64 + nj * 16 + l15] = f2bf(v);
            }
        }
    }
    #pragma unroll
    for (int nj = 0; nj < 4; ++nj) {
        ps[nj] += __shfl_xor(ps[nj], 16, 64);
        ps[nj] += __shfl_xor(ps[nj], 32, 64);
    }
    __syncthreads();    // safe to overlay s_pool on s_in
    if (l4 == 0) {
        #pragma unroll
        for (int nj = 0; nj < 4; ++nj)
            s_pool[w * 64 + nj * 16 + l15] = ps[nj];
    }
    __syncthreads();
    partial[((size_t)n * NTILE + tile) * 128 + tid] = s_pool[tid];
}

// ---------------- per-(depth,sample): reduce partials + 100 dot-128 ----------------
__global__ __launch_bounds__(128) void logits_k(
    const float* __restrict__ partial,  // [4][16][98][128]
    const float* __restrict__ cw,       // [4][100][128]
    const float* __restrict__ cb,       // [4][100]
    float* __restrict__ lg)             // [4][16][100]
{
    const int i = blockIdx.x, n = blockIdx.y;
    const int tid = threadIdx.x;
    __shared__ float pool[128];
    const float* pp = partial + ((size_t)(i * NB + n) * NTILE) * 128;
    float s = 0.f;
    for (int t = 0; t < NTILE; ++t) s += pp[t * 128 + tid];
    pool[tid] = s * (1.f / HW);
    __syncthreads();
    if (tid < NCLS) {
        const float* wp = cw + ((size_t)i * NCLS + tid) * CCH;
        float a = cb[i * NCLS + tid];
        #pragma unroll
        for (int c = 0; c < CCH; c += 4) {
            float4 w4 = *(const float4*)(wp + c);
            a += pool[c] * w4.x + pool[c + 1] * w4.y
               + pool[c + 2] * w4.z + pool[c + 3] * w4.w;
        }
        lg[(i * NB + n) * NCLS + tid] = a;
    }
}

// ---------------- early-exit selection ----------------
__global__ __launch_bounds__(256) void select_k(
    const float* __restrict__ lg,   // [4][16][100]
    float* __restrict__ out)        // [16][100]
{
    __shared__ float slg[4 * NB * NCLS];
    __shared__ int chosen[NB];
    const int tid = threadIdx.x;
    for (int e = tid; e < 4 * NB * NCLS; e += 256) slg[e] = lg[e];
    __syncthreads();
    if (tid < NB) {
        int n = tid, ch = 3;
        for (int i = 0; i < 3; i++) {
            const float* row = &slg[(i * NB + n) * NCLS];
            float m = -1e30f;
            for (int j = 0; j < NCLS; j++) m = fmaxf(m, row[j]);
            float se = 0.f;
            for (int j = 0; j < NCLS; j++) se += expf(row[j] - m);
            if (1.f / se >= 0.9f) { ch = i; break; }
        }
        chosen[n] = ch;
    }
    __syncthreads();
    for (int e = tid; e < NB * NCLS; e += 256) {
        int n = e / NCLS, j = e % NCLS;
        out[e] = slg[(chosen[n] * NB + n) * NCLS + j];
    }
}

extern "C" void kernel_launch(void* const* d_in, const int* in_sizes, int n_in,
                              void* d_out, int out_size, void* d_ws, size_t ws_size,
                              hipStream_t stream) {
    const float* x       = (const float*)d_in[0];
    const float* init_w  = (const float*)d_in[1];
    const float* init_b  = (const float*)d_in[2];
    const float* block_w = (const float*)d_in[3];
    const float* block_b = (const float*)d_in[4];
    const float* cls_w   = (const float*)d_in[5];
    const float* cls_b   = (const float*)d_in[6];
    float* out = (float*)d_out;

    char* ws = (char*)d_ws;
    u16* fA        = (u16*)ws;                      // 51,380,224 B
    u16* fB        = (u16*)(ws + 51380224);         // 51,380,224 B
    u16* wb        = (u16*)(ws + 102760448);        //  1,179,648 B
    float* partial = (float*)(ws + 103940096);      // 4*16*98*128*4 = 3,211,264 B
    float* lgbuf   = (float*)(ws + 107151360);      // 4*16*100*4 = 25,600 B

    convert_w<<<2304, 256, 0, stream>>>(block_w, wb);
    conv_init<<<dim3(49, 4, NB), 256, 0, stream>>>(
        x, init_w + 2 * 128 * 27, init_b + 2 * 128, fA);

    u16* cur = fA;
    u16* nxt = fB;
    for (int i = 0; i < 4; ++i) {
        if (i < 3)
            conv_mfma<true><<<dim3(NTILE, NB), 128, 0, stream>>>(
                cur, wb + (size_t)i * 147456, block_b + (i * 3 + 2) * 128, nxt,
                partial + (size_t)i * NB * NTILE * 128);
        else
            conv_mfma<false><<<dim3(NTILE, NB), 128, 0, stream>>>(
                cur, wb + (size_t)i * 147456, block_b + (i * 3 + 2) * 128, nxt,
                partial + (size_t)i * NB * NTILE * 128);
        u16* t = cur; cur = nxt; nxt = t;
    }

    logits_k<<<dim3(4, NB), 128, 0, stream>>>(partial, cls_w, cls_b, lgbuf);
    select_k<<<1, 256, 0, stream>>>(lgbuf, out);
}

// Round 11
// 327.350 us; speedup vs baseline: 1.1519x; 1.1519x over previous
//
#include <hip/hip_runtime.h>
#include <hip/hip_bf16.h>

// MSDNet on MI355X. Only scale 2's chain matters (scales 0/1 dead), and
// final_logits == logits at depth 3.
// conv_mfma v7 = r9 (best, 77.5us/conv) + two levers:
//   (1) B/W LDS layout: stride 32 (no pad) + XOR granule swizzle
//       (r10's measured-low-conflict config), same involution on write+read.
//   (2) W quad-buffer -> ONE barrier per 2 K-steps (18 phases) instead of 36.
// Geometry unchanged: 256 thr / 4 waves of 64px x 64co (3 waves/SIMD,
// 3 blocks/CU), q-streamed A chunks (s_in 14.4KB), reg-prefetch W depth 2.

typedef unsigned int uint;
typedef unsigned short u16;
typedef __bf16 bf16x8 __attribute__((ext_vector_type(8)));
typedef short short8 __attribute__((ext_vector_type(8)));
typedef unsigned short ushort8 __attribute__((ext_vector_type(8)));
typedef float f32x4 __attribute__((ext_vector_type(4)));

#define NB   16
#define CCH  128
#define NCLS 100
#define HW   12544      // 112*112
#define NTILE 98        // 14 h-tiles x 7 w-tiles per image

__device__ __forceinline__ u16 f2bf(float f) {
    uint u = __float_as_uint(f);
    return (u16)((u + 0x7fffu + ((u >> 16) & 1u)) >> 16);
}

// ---------------- weight transpose+convert: block_w[d][2][co][ci][kh][kw] f32
// -> wb[d][tap][co][ci] bf16 ----------------
__global__ __launch_bounds__(256) void convert_w(
    const float* __restrict__ bw, u16* __restrict__ wb)
{
    int idx = blockIdx.x * 256 + threadIdx.x;        // 4*9*128*128
    if (idx >= 4 * 9 * 16384) return;
    int d = idx / 147456, r = idx % 147456;
    int t = r / 16384, r2 = r & 16383;
    int co = r2 >> 7, ci = r2 & 127;
    float v = bw[((size_t)(d * 3 + 2) * 16384 + co * 128 + ci) * 9 + t];
    wb[idx] = f2bf(v);
}

// ---------------- init conv: cin=3, fp32 VALU, NCHW fp32 in -> NHWC bf16 out ----------------
__global__ __launch_bounds__(256) void conv_init(
    const float* __restrict__ in,    // [16][3][112][112]
    const float* __restrict__ wgt,   // [128][3][3][3]
    const float* __restrict__ bias,  // [128]
    u16* __restrict__ outp)          // [16][12544][128] bf16
{
    const int tile = blockIdx.x;          // 0..48 (16x16 tiles)
    const int cg   = blockIdx.y;          // 0..3  (32 couts)
    const int n    = blockIdx.z;
    const int h0 = (tile / 7) * 16, w0 = (tile % 7) * 16;
    const int tid = threadIdx.x;
    const int sid = tid & 63, wv = tid >> 6;
    const int tx = sid & 7, ty = sid >> 3;

    __shared__ float s_in[3][18][18];
    __shared__ float s_w[3][9][32];

    float acc[2][2][8];
    #pragma unroll
    for (int a = 0; a < 2; a++)
        #pragma unroll
        for (int b = 0; b < 2; b++)
            #pragma unroll
            for (int c = 0; c < 8; c++) acc[a][b][c] = 0.f;

    const float* in_n = in + (size_t)n * 3 * HW;
    const int cbase = cg * 32;

    for (int e = tid; e < 3 * 324; e += 256) {
        int ck = e / 324, p = e % 324;
        int y = p / 18, x = p % 18;
        int gh = h0 + y - 1, gw = w0 + x - 1;
        float v = 0.f;
        if ((unsigned)gh < 112u && (unsigned)gw < 112u)
            v = in_n[(size_t)ck * HW + gh * 112 + gw];
        s_in[ck][y][x] = v;
    }
    for (int e = tid; e < 3 * 9 * 32; e += 256) {
        int co = e / 27, r = e % 27;
        int ck = r / 9, kidx = r % 9;
        s_w[ck][kidx][co] = wgt[((size_t)(cbase + co) * 3 + ck) * 9 + kidx];
    }
    __syncthreads();

    #pragma unroll
    for (int ck = 0; ck < 3; ck++) {
        float rowv[4][4];
        #pragma unroll
        for (int r = 0; r < 4; r++) {
            float2 a  = *(const float2*)&s_in[ck][ty * 2 + r][tx * 2];
            float2 b2 = *(const float2*)&s_in[ck][ty * 2 + r][tx * 2 + 2];
            rowv[r][0] = a.x; rowv[r][1] = a.y;
            rowv[r][2] = b2.x; rowv[r][3] = b2.y;
        }
        #pragma unroll
        for (int kh = 0; kh < 3; kh++)
            #pragma unroll
            for (int kw = 0; kw < 3; kw++) {
                float i00 = rowv[kh][kw],     i01 = rowv[kh][kw + 1];
                float i10 = rowv[kh + 1][kw], i11 = rowv[kh + 1][kw + 1];
                const float* wp = &s_w[ck][kh * 3 + kw][wv * 8];
                #pragma unroll
                for (int co = 0; co < 8; co++) {
                    float wval = wp[co];
                    acc[0][0][co] += i00 * wval;
                    acc[0][1][co] += i01 * wval;
                    acc[1][0][co] += i10 * wval;
                    acc[1][1][co] += i11 * wval;
                }
            }
    }

    float bv[8];
    #pragma unroll
    for (int co = 0; co < 8; co++) bv[co] = bias[cbase + wv * 8 + co];
    #pragma unroll
    for (int dy = 0; dy < 2; dy++)
        #pragma unroll
        for (int dx = 0; dx < 2; dx++) {
            ushort8 pk;
            #pragma unroll
            for (int co = 0; co < 8; co++)
                pk[co] = f2bf(acc[dy][dx][co] + bv[co]);   // no relu on init
            int h = h0 + ty * 2 + dy, w = w0 + tx * 2 + dx;
            *(ushort8*)(outp + (((size_t)n * HW + h * 112 + w) << 7) + cbase + wv * 8) = pk;
        }
}

// ---------------- MFMA implicit-GEMM 3x3 conv, 128->128, bf16 NHWC ----------------
// Block: 256 thr (4 waves), tile M=128 px (8 rows x 16 cols), N=128 couts.
// Wave: 64px x 64co (acc[4][4], ~150 total regs -> 3 waves/SIMD).
// 36 K-steps (s = q*9 + tap), phases of 2 steps with ONE barrier each.
// W: quad-buffered s_w[4][128*32] (XOR-swizzled granules), reg prefetch
// depth 2 pairs. A: s_in[180][40] per-q chunk, restaged at q boundaries.
#define AS 40           // s_in elems per px (32 + 8 pad) -> 80B stride

template<bool STORE>
__global__ __launch_bounds__(256, 3) void conv_mfma(
    const u16* __restrict__ in,     // [16][12544][128] bf16
    const u16* __restrict__ wb,     // [9][128][128] bf16 (tap, cout, cin)
    const float* __restrict__ bias, // [128]
    u16* __restrict__ outp,         // [16][12544][128] bf16 (unused if !STORE)
    float* __restrict__ partial)    // [16][98][128] f32 per-block pooled sums
{
    __shared__ u16 s_in[180 * AS];          // 14,400 B
    __shared__ u16 s_w[4][128 * 32];        // 32,768 B quad-buffer, stride 32
    float* s_pool = (float*)s_in;           // overlay (after K-loop)

    const int tile = blockIdx.x;            // 0..97
    const int n    = blockIdx.y;
    const int h0 = (tile / 7) * 8, w0 = (tile % 7) * 16;
    const int tid = threadIdx.x, lane = tid & 63;
    const int wid = tid >> 6, wm = wid >> 1, wn = wid & 1;
    const int l15 = lane & 15, l4 = lane >> 4;

    const u16* in_n = in + ((size_t)n * HW << 7);

    // W staging roles: thread handles couts co0, co0+64; 8 cin elems each.
    // LDS slot (co, gpos) holds SOURCE granule gpos ^ ((co>>1)&3).
    const int co0 = tid >> 2;
    const int g0  = (tid & 3) ^ ((tid >> 3) & 3);    // source granule to fetch
    const int k0  = g0 << 3;                          // global elem offset
    const int wp0 = (tid & 3) << 3;                   // LDS granule pos (elems)

    // ---- prologue: stage W(0)->buf0, W(1)->buf1 (direct reg->LDS) ----
    #pragma unroll
    for (int s01 = 0; s01 < 2; ++s01) {
        const u16* src = wb + s01 * 16384;            // tap s01, q=0
        uint4 va = *(const uint4*)(src + (co0 << 7) + k0);
        uint4 vb = *(const uint4*)(src + ((co0 + 64) << 7) + k0);
        *(uint4*)(&s_w[s01][co0 * 32] + wp0) = va;
        *(uint4*)(&s_w[s01][(co0 + 64) * 32] + wp0) = vb;
    }
    // preload regs: wA = W(2), wB = W(3)
    uint4 wA0, wA1, wB0, wB1;
    {
        const u16* s2 = wb + 2 * 16384;
        const u16* s3 = wb + 3 * 16384;
        wA0 = *(const uint4*)(s2 + (co0 << 7) + k0);
        wA1 = *(const uint4*)(s2 + ((co0 + 64) << 7) + k0);
        wB0 = *(const uint4*)(s3 + (co0 << 7) + k0);
        wB1 = *(const uint4*)(s3 + ((co0 + 64) << 7) + k0);
    }

    // ---- stage A(q=0): 180 px x 32 cin (halo, zero-padded) ----
    #pragma unroll
    for (int r2 = 0; r2 < 3; ++r2) {
        int g = tid + (r2 << 8);
        if (g < 720) {
            int px = g >> 2, c8 = (g & 3) << 3;
            int hh = px / 18, ww2 = px - hh * 18;
            int gh = h0 + hh - 1, gw = w0 + ww2 - 1;
            uint4 v = make_uint4(0, 0, 0, 0);
            if ((unsigned)gh < 112u && (unsigned)gw < 112u)
                v = *(const uint4*)(in_n + ((size_t)(gh * 112 + gw) << 7) + c8);
            *(uint4*)(s_in + px * AS + c8) = v;
        }
    }

    f32x4 acc[4][4];
    #pragma unroll
    for (int i = 0; i < 4; ++i)
        #pragma unroll
        for (int j = 0; j < 4; ++j)
            #pragma unroll
            for (int e = 0; e < 4; ++e) acc[i][j][e] = 0.f;

    int a_base[4], b_base[4];
    #pragma unroll
    for (int fi = 0; fi < 4; ++fi) a_base[fi] = (wm * 4 + fi) * 18 + l15;
    #pragma unroll
    for (int nj = 0; nj < 4; ++nj)
        b_base[nj] = (wn * 64 + nj * 16 + l15) * 32 + ((l4 ^ ((l15 >> 1) & 3)) << 3);

    __syncthreads();    // A(0) + W bufs 0,1 visible

    #pragma unroll
    for (int P = 0; P < 18; ++P) {
        const int s0 = 2 * P, s1 = 2 * P + 1;

        // ================= step s0 (consume buf s0%4, wA) =================
        {
            const int t = s0 % 9, kh = t / 3, kw = t - kh * 3;
            bf16x8 a[4], b[4];
            #pragma unroll
            for (int fi = 0; fi < 4; ++fi) {
                const u16* p = s_in + (a_base[fi] + kh * 18 + kw) * AS + (l4 << 3);
                a[fi] = __builtin_bit_cast(bf16x8, *(const short8*)p);
            }
            const u16* rb = &s_w[s0 & 3][0];
            #pragma unroll
            for (int nj = 0; nj < 4; ++nj)
                b[nj] = __builtin_bit_cast(bf16x8, *(const short8*)(rb + b_base[nj]));

            uint4 nA0, nA1;
            if (s0 + 4 < 36) {      // prefetch W(s0+4)
                const u16* srcn = wb + ((s0 + 4) % 9) * 16384 + ((s0 + 4) / 9) * 32;
                nA0 = *(const uint4*)(srcn + (co0 << 7) + k0);
                nA1 = *(const uint4*)(srcn + ((co0 + 64) << 7) + k0);
            }

            #pragma unroll
            for (int fi = 0; fi < 4; ++fi)
                #pragma unroll
                for (int nj = 0; nj < 4; ++nj)
                    acc[fi][nj] = __builtin_amdgcn_mfma_f32_16x16x32_bf16(
                        a[fi], b[nj], acc[fi][nj], 0, 0, 0);

            if (s0 + 2 < 36) {      // ds_write W(s0+2) -> buf (s0+2)%4
                u16* wd = &s_w[(s0 + 2) & 3][0];
                *(uint4*)(wd + co0 * 32 + wp0) = wA0;
                *(uint4*)(wd + (co0 + 64) * 32 + wp0) = wA1;
            }
            if (s0 + 4 < 36) { wA0 = nA0; wA1 = nA1; }
        }

        // -------- mid-phase q-restage (boundary between s0,s1) --------
        if (s0 % 9 == 8) {
            const int qn = s0 / 9 + 1;
            asm volatile("s_waitcnt lgkmcnt(0)" ::: "memory");
            __builtin_amdgcn_s_barrier();       // all waves done reading q
            #pragma unroll
            for (int r2 = 0; r2 < 3; ++r2) {
                int g = tid + (r2 << 8);
                if (g < 720) {
                    int px = g >> 2, c8 = (g & 3) << 3;
                    int hh = px / 18, ww2 = px - hh * 18;
                    int gh = h0 + hh - 1, gw = w0 + ww2 - 1;
                    uint4 v = make_uint4(0, 0, 0, 0);
                    if ((unsigned)gh < 112u && (unsigned)gw < 112u)
                        v = *(const uint4*)(in_n + ((size_t)(gh * 112 + gw) << 7)
                                            + (qn << 5) + c8);
                    *(uint4*)(s_in + px * AS + c8) = v;
                }
            }
            asm volatile("s_waitcnt lgkmcnt(0)" ::: "memory");
            __builtin_amdgcn_s_barrier();       // new A visible
            __builtin_amdgcn_sched_barrier(0);
        }

        // ================= step s1 (consume buf s1%4, wB) =================
        {
            const int t = s1 % 9, kh = t / 3, kw = t - kh * 3;
            bf16x8 a[4], b[4];
            #pragma unroll
            for (int fi = 0; fi < 4; ++fi) {
                const u16* p = s_in + (a_base[fi] + kh * 18 + kw) * AS + (l4 << 3);
                a[fi] = __builtin_bit_cast(bf16x8, *(const short8*)p);
            }
            const u16* rb = &s_w[s1 & 3][0];
            #pragma unroll
            for (int nj = 0; nj < 4; ++nj)
                b[nj] = __builtin_bit_cast(bf16x8, *(const short8*)(rb + b_base[nj]));

            uint4 nB0, nB1;
            if (s1 + 4 < 36) {      // prefetch W(s1+4)
                const u16* srcn = wb + ((s1 + 4) % 9) * 16384 + ((s1 + 4) / 9) * 32;
                nB0 = *(const uint4*)(srcn + (co0 << 7) + k0);
                nB1 = *(const uint4*)(srcn + ((co0 + 64) << 7) + k0);
            }

            #pragma unroll
            for (int fi = 0; fi < 4; ++fi)
                #pragma unroll
                for (int nj = 0; nj < 4; ++nj)
                    acc[fi][nj] = __builtin_amdgcn_mfma_f32_16x16x32_bf16(
                        a[fi], b[nj], acc[fi][nj], 0, 0, 0);

            if (s1 + 2 < 36) {      // ds_write W(s1+2) -> buf (s1+2)%4
                u16* wd = &s_w[(s1 + 2) & 3][0];
                *(uint4*)(wd + co0 * 32 + wp0) = wB0;
                *(uint4*)(wd + (co0 + 64) * 32 + wp0) = wB1;
            }
            if (s1 + 4 < 36) { wB0 = nB0; wB1 = nB1; }
        }

        // ---- end-of-phase barrier (staged W becomes visible) ----
        asm volatile("s_waitcnt lgkmcnt(0)" ::: "memory");
        __builtin_amdgcn_s_barrier();
        __builtin_amdgcn_sched_barrier(0);

        // -------- phase-boundary q-restage (boundary after s1) --------
        if (s1 % 9 == 8 && s1 != 35) {
            const int qn = s1 / 9 + 1;
            #pragma unroll
            for (int r2 = 0; r2 < 3; ++r2) {
                int g = tid + (r2 << 8);
                if (g < 720) {
                    int px = g >> 2, c8 = (g & 3) << 3;
                    int hh = px / 18, ww2 = px - hh * 18;
                    int gh = h0 + hh - 1, gw = w0 + ww2 - 1;
                    uint4 v = make_uint4(0, 0, 0, 0);
                    if ((unsigned)gh < 112u && (unsigned)gw < 112u)
                        v = *(const uint4*)(in_n + ((size_t)(gh * 112 + gw) << 7)
                                            + (qn << 5) + c8);
                    *(uint4*)(s_in + px * AS + c8) = v;
                }
            }
            asm volatile("s_waitcnt lgkmcnt(0)" ::: "memory");
            __builtin_amdgcn_s_barrier();
            __builtin_amdgcn_sched_barrier(0);
        }
    }

    // ---- epilogue: bias + relu, optional bf16 NHWC stores, fused pooling ----
    // D layout: col = lane&15 (cout), row = l4*4 + j (pixel-within-16)
    float bv[4], ps[4];
    #pragma unroll
    for (int nj = 0; nj < 4; ++nj) { bv[nj] = bias[wn * 64 + nj * 16 + l15]; ps[nj] = 0.f; }
    u16* out_n = outp + ((size_t)n * HW << 7);
    #pragma unroll
    for (int fi = 0; fi < 4; ++fi) {
        int h = h0 + wm * 4 + fi;
        #pragma unroll
        for (int j = 0; j < 4; ++j) {
            int w = w0 + (l4 << 2) + j;
            u16* pr = out_n + ((size_t)(h * 112 + w) << 7);
            #pragma unroll
            for (int nj = 0; nj < 4; ++nj) {
                float v = fmaxf(acc[fi][nj][j] + bv[nj], 0.f);
                ps[nj] += v;
                if (STORE) pr[wn * 64 + nj * 16 + l15] = f2bf(v);
            }
        }
    }
    #pragma unroll
    for (int nj = 0; nj < 4; ++nj) {
        ps[nj] += __shfl_xor(ps[nj], 16, 64);
        ps[nj] += __shfl_xor(ps[nj], 32, 64);
    }
    __syncthreads();    // all s_in reads long done; reuse as pool buffer
    if (l4 == 0) {
        #pragma unroll
        for (int nj = 0; nj < 4; ++nj)
            s_pool[wm * 128 + wn * 64 + nj * 16 + l15] = ps[nj];
    }
    __syncthreads();
    if (tid < 128)
        partial[((size_t)n * NTILE + tile) * 128 + tid] = s_pool[tid] + s_pool[128 + tid];
}

// ---------------- per-(depth,sample): reduce partials + 100 dot-128 ----------------
__global__ __launch_bounds__(128) void logits_k(
    const float* __restrict__ partial,  // [4][16][98][128]
    const float* __restrict__ cw,       // [4][100][128]
    const float* __restrict__ cb,       // [4][100]
    float* __restrict__ lg)             // [4][16][100]
{
    const int i = blockIdx.x, n = blockIdx.y;
    const int tid = threadIdx.x;
    __shared__ float pool[128];
    const float* pp = partial + ((size_t)(i * NB + n) * NTILE) * 128;
    float s = 0.f;
    for (int t = 0; t < NTILE; ++t) s += pp[t * 128 + tid];
    pool[tid] = s * (1.f / HW);
    __syncthreads();
    if (tid < NCLS) {
        const float* wp = cw + ((size_t)i * NCLS + tid) * CCH;
        float a = cb[i * NCLS + tid];
        #pragma unroll
        for (int c = 0; c < CCH; c += 4) {
            float4 w4 = *(const float4*)(wp + c);
            a += pool[c] * w4.x + pool[c + 1] * w4.y
               + pool[c + 2] * w4.z + pool[c + 3] * w4.w;
        }
        lg[(i * NB + n) * NCLS + tid] = a;
    }
}

// ---------------- early-exit selection ----------------
__global__ __launch_bounds__(256) void select_k(
    const float* __restrict__ lg,   // [4][16][100]
    float* __restrict__ out)        // [16][100]
{
    __shared__ float slg[4 * NB * NCLS];
    __shared__ int chosen[NB];
    const int tid = threadIdx.x;
    for (int e = tid; e < 4 * NB * NCLS; e += 256) slg[e] = lg[e];
    __syncthreads();
    if (tid < NB) {
        int n = tid, ch = 3;
        for (int i = 0; i < 3; i++) {
            const float* row = &slg[(i * NB + n) * NCLS];
            float m = -1e30f;
            for (int j = 0; j < NCLS; j++) m = fmaxf(m, row[j]);
            float se = 0.f;
            for (int j = 0; j < NCLS; j++) se += expf(row[j] - m);
            if (1.f / se >= 0.9f) { ch = i; break; }
        }
        chosen[n] = ch;
    }
    __syncthreads();
    for (int e = tid; e < NB * NCLS; e += 256) {
        int n = e / NCLS, j = e % NCLS;
        out[e] = slg[(chosen[n] * NB + n) * NCLS + j];
    }
}

extern "C" void kernel_launch(void* const* d_in, const int* in_sizes, int n_in,
                              void* d_out, int out_size, void* d_ws, size_t ws_size,
                              hipStream_t stream) {
    const float* x       = (const float*)d_in[0];
    const float* init_w  = (const float*)d_in[1];
    const float* init_b  = (const float*)d_in[2];
    const float* block_w = (const float*)d_in[3];
    const float* block_b = (const float*)d_in[4];
    const float* cls_w   = (const float*)d_in[5];
    const float* cls_b   = (const float*)d_in[6];
    float* out = (float*)d_out;

    char* ws = (char*)d_ws;
    u16* fA        = (u16*)ws;                      // 51,380,224 B
    u16* fB        = (u16*)(ws + 51380224);         // 51,380,224 B
    u16* wb        = (u16*)(ws + 102760448);        //  1,179,648 B
    float* partial = (float*)(ws + 103940096);      // 4*16*98*128*4 = 3,211,264 B
    float* lgbuf   = (float*)(ws + 107151360);      // 4*16*100*4 = 25,600 B

    convert_w<<<2304, 256, 0, stream>>>(block_w, wb);
    conv_init<<<dim3(49, 4, NB), 256, 0, stream>>>(
        x, init_w + 2 * 128 * 27, init_b + 2 * 128, fA);

    u16* cur = fA;
    u16* nxt = fB;
    for (int i = 0; i < 4; ++i) {
        if (i < 3)
            conv_mfma<true><<<dim3(NTILE, NB), 256, 0, stream>>>(
                cur, wb + (size_t)i * 147456, block_b + (i * 3 + 2) * 128, nxt,
                partial + (size_t)i * NB * NTILE * 128);
        else
            conv_mfma<false><<<dim3(NTILE, NB), 256, 0, stream>>>(
                cur, wb + (size_t)i * 147456, block_b + (i * 3 + 2) * 128, nxt,
                partial + (size_t)i * NB * NTILE * 128);
        u16* t = cur; cur = nxt; nxt = t;
    }

    logits_k<<<dim3(4, NB), 128, 0, stream>>>(partial, cls_w, cls_b, lgbuf);
    select_k<<<1, 256, 0, stream>>>(lgbuf, out);
}

// Round 12
// 315.572 us; speedup vs baseline: 1.1949x; 1.0373x over previous
//
#include <hip/hip_runtime.h>
#include <hip/hip_bf16.h>

// MSDNet on MI355X. Only scale 2's chain matters (scales 0/1 dead), and
// final_logits == logits at depth 3.
// conv_mfma v8 = v7 (72.6us/conv) with W staged via BLOCK-COOPERATIVE
// global_load_lds from a pre-swizzled global image (convert_w emits per-step
// 8KB LDS images, XOR granule swizzle baked in): no W ds_writes, no W
// reg-prefetch, quad-buffer + vmcnt(0)+raw-barrier once per 2 steps.
// Geometry unchanged: 256 thr / 4 waves of 64px x 64co, 3 blocks/CU,
// q-streamed A chunks (s_in 14.4KB).

typedef unsigned int uint;
typedef unsigned short u16;
typedef __bf16 bf16x8 __attribute__((ext_vector_type(8)));
typedef short short8 __attribute__((ext_vector_type(8)));
typedef unsigned short ushort8 __attribute__((ext_vector_type(8)));
typedef float f32x4 __attribute__((ext_vector_type(4)));

#define NB   16
#define CCH  128
#define NCLS 100
#define HW   12544      // 112*112
#define NTILE 98        // 14 h-tiles x 7 w-tiles per image

__device__ __forceinline__ u16 f2bf(float f) {
    uint u = __float_as_uint(f);
    return (u16)((u + 0x7fffu + ((u >> 16) & 1u)) >> 16);
}

__device__ __forceinline__ void gload16(const u16* g, u16* l) {
    __builtin_amdgcn_global_load_lds(
        (const __attribute__((address_space(1))) uint*)g,
        (__attribute__((address_space(3))) uint*)l, 16, 0, 0);
}

// ---------------- weight convert: block_w[d][2][co][ci][kh][kw] f32 ->
// per-step LDS images wbs[d][s][4096]: slot (co,gpos,e) holds
// W[tap(s)][co][ q(s)*32 + (gpos ^ ((co>>1)&3))*8 + e ]   (s = q*9 + tap)
// Staged to LDS verbatim by linear gload16; read side applies the same XOR.
__global__ __launch_bounds__(256) void convert_w(
    const float* __restrict__ bw, u16* __restrict__ wbs)
{
    int idx = blockIdx.x * 256 + threadIdx.x;        // 4 * 36 * 4096
    if (idx >= 4 * 147456) return;
    int d = idx / 147456, r = idx % 147456;
    int s = r >> 12;                 // 0..35
    int p = r & 4095;
    int co = p >> 5, gpos = (p >> 3) & 3, e = p & 7;
    int q = s / 9, t = s % 9;
    int cin = q * 32 + ((gpos ^ ((co >> 1) & 3)) << 3) + e;
    float v = bw[(((size_t)(d * 3 + 2) * 128 + co) * 128 + cin) * 9 + t];
    wbs[idx] = f2bf(v);
}

// ---------------- init conv: cin=3, fp32 VALU, NCHW fp32 in -> NHWC bf16 out ----------------
__global__ __launch_bounds__(256) void conv_init(
    const float* __restrict__ in,    // [16][3][112][112]
    const float* __restrict__ wgt,   // [128][3][3][3]
    const float* __restrict__ bias,  // [128]
    u16* __restrict__ outp)          // [16][12544][128] bf16
{
    const int tile = blockIdx.x;          // 0..48 (16x16 tiles)
    const int cg   = blockIdx.y;          // 0..3  (32 couts)
    const int n    = blockIdx.z;
    const int h0 = (tile / 7) * 16, w0 = (tile % 7) * 16;
    const int tid = threadIdx.x;
    const int sid = tid & 63, wv = tid >> 6;
    const int tx = sid & 7, ty = sid >> 3;

    __shared__ float s_in[3][18][18];
    __shared__ float s_w[3][9][32];

    float acc[2][2][8];
    #pragma unroll
    for (int a = 0; a < 2; a++)
        #pragma unroll
        for (int b = 0; b < 2; b++)
            #pragma unroll
            for (int c = 0; c < 8; c++) acc[a][b][c] = 0.f;

    const float* in_n = in + (size_t)n * 3 * HW;
    const int cbase = cg * 32;

    for (int e = tid; e < 3 * 324; e += 256) {
        int ck = e / 324, p = e % 324;
        int y = p / 18, x = p % 18;
        int gh = h0 + y - 1, gw = w0 + x - 1;
        float v = 0.f;
        if ((unsigned)gh < 112u && (unsigned)gw < 112u)
            v = in_n[(size_t)ck * HW + gh * 112 + gw];
        s_in[ck][y][x] = v;
    }
    for (int e = tid; e < 3 * 9 * 32; e += 256) {
        int co = e / 27, r = e % 27;
        int ck = r / 9, kidx = r % 9;
        s_w[ck][kidx][co] = wgt[((size_t)(cbase + co) * 3 + ck) * 9 + kidx];
    }
    __syncthreads();

    #pragma unroll
    for (int ck = 0; ck < 3; ck++) {
        float rowv[4][4];
        #pragma unroll
        for (int r = 0; r < 4; r++) {
            float2 a  = *(const float2*)&s_in[ck][ty * 2 + r][tx * 2];
            float2 b2 = *(const float2*)&s_in[ck][ty * 2 + r][tx * 2 + 2];
            rowv[r][0] = a.x; rowv[r][1] = a.y;
            rowv[r][2] = b2.x; rowv[r][3] = b2.y;
        }
        #pragma unroll
        for (int kh = 0; kh < 3; kh++)
            #pragma unroll
            for (int kw = 0; kw < 3; kw++) {
                float i00 = rowv[kh][kw],     i01 = rowv[kh][kw + 1];
                float i10 = rowv[kh + 1][kw], i11 = rowv[kh + 1][kw + 1];
                const float* wp = &s_w[ck][kh * 3 + kw][wv * 8];
                #pragma unroll
                for (int co = 0; co < 8; co++) {
                    float wval = wp[co];
                    acc[0][0][co] += i00 * wval;
                    acc[0][1][co] += i01 * wval;
                    acc[1][0][co] += i10 * wval;
                    acc[1][1][co] += i11 * wval;
                }
            }
    }

    float bv[8];
    #pragma unroll
    for (int co = 0; co < 8; co++) bv[co] = bias[cbase + wv * 8 + co];
    #pragma unroll
    for (int dy = 0; dy < 2; dy++)
        #pragma unroll
        for (int dx = 0; dx < 2; dx++) {
            ushort8 pk;
            #pragma unroll
            for (int co = 0; co < 8; co++)
                pk[co] = f2bf(acc[dy][dx][co] + bv[co]);   // no relu on init
            int h = h0 + ty * 2 + dy, w = w0 + tx * 2 + dx;
            *(ushort8*)(outp + (((size_t)n * HW + h * 112 + w) << 7) + cbase + wv * 8) = pk;
        }
}

// ---------------- MFMA implicit-GEMM 3x3 conv, 128->128, bf16 NHWC ----------------
// Block: 256 thr (4 waves), tile M=128 px (8 rows x 16 cols), N=128 couts.
// Wave: 64px x 64co (acc[4][4]). 36 K-steps (s = q*9 + tap), 18 phases of 2.
// W: quad-buffered s_w[4][4096] filled by block-cooperative gload16 from the
// pre-swizzled global image (2 instr/wave/step), batch(P+1) issued at phase-P
// start, vmcnt(0) + raw barrier at phase end. A: s_in[180][40] per-q chunk.
#define AS 40           // s_in elems per px (32 + 8 pad) -> 80B stride

template<bool STORE>
__global__ __launch_bounds__(256, 3) void conv_mfma(
    const u16* __restrict__ in,     // [16][12544][128] bf16
    const u16* __restrict__ wbs,    // [36][4096] bf16 per-step LDS images
    const float* __restrict__ bias, // [128]
    u16* __restrict__ outp,         // [16][12544][128] bf16 (unused if !STORE)
    float* __restrict__ partial)    // [16][98][128] f32 per-block pooled sums
{
    __shared__ u16 s_in[180 * AS];          // 14,400 B
    __shared__ u16 s_w[4][4096];            // 32,768 B quad-buffer
    float* s_pool = (float*)s_in;           // overlay (after K-loop)

    const int tile = blockIdx.x;            // 0..97
    const int n    = blockIdx.y;
    const int h0 = (tile / 7) * 8, w0 = (tile % 7) * 16;
    const int tid = threadIdx.x, lane = tid & 63;
    const int wid = tid >> 6, wm = wid >> 1, wn = wid & 1;
    const int l15 = lane & 15, l4 = lane >> 4;

    const u16* in_n = in + ((size_t)n * HW << 7);

    // W staging: wave wid covers elems [wid*1024, wid*1024+1024) of each step
    // image via 2 gload16 (lane-linear dest, coalesced source).
    const u16* wsrc_base = wbs + wid * 1024 + (lane << 3);
    u16* wdst_base = &s_w[0][0] + wid * 1024;

    // ---- prologue: issue W(0), W(1) ----
    #pragma unroll
    for (int s01 = 0; s01 < 2; ++s01) {
        const u16* src = wsrc_base + (s01 << 12);
        u16* dst = wdst_base + (s01 << 12);
        gload16(src, dst);
        gload16(src + 512, dst + 512);
    }

    // ---- stage A(q=0): 180 px x 32 cin (halo, zero-padded) ----
    #pragma unroll
    for (int r2 = 0; r2 < 3; ++r2) {
        int g = tid + (r2 << 8);
        if (g < 720) {
            int px = g >> 2, c8 = (g & 3) << 3;
            int hh = px / 18, ww2 = px - hh * 18;
            int gh = h0 + hh - 1, gw = w0 + ww2 - 1;
            uint4 v = make_uint4(0, 0, 0, 0);
            if ((unsigned)gh < 112u && (unsigned)gw < 112u)
                v = *(const uint4*)(in_n + ((size_t)(gh * 112 + gw) << 7) + c8);
            *(uint4*)(s_in + px * AS + c8) = v;
        }
    }

    f32x4 acc[4][4];
    #pragma unroll
    for (int i = 0; i < 4; ++i)
        #pragma unroll
        for (int j = 0; j < 4; ++j)
            #pragma unroll
            for (int e = 0; e < 4; ++e) acc[i][j][e] = 0.f;

    int a_base[4], b_base[4];
    #pragma unroll
    for (int fi = 0; fi < 4; ++fi) a_base[fi] = (wm * 4 + fi) * 18 + l15;
    #pragma unroll
    for (int nj = 0; nj < 4; ++nj)
        b_base[nj] = (wn * 64 + nj * 16 + l15) * 32 + ((l4 ^ ((l15 >> 1) & 3)) << 3);

    __syncthreads();    // drains vmcnt: A(0) + W bufs 0,1 in LDS

    #pragma unroll
    for (int P = 0; P < 18; ++P) {
        const int s0 = 2 * P, s1 = 2 * P + 1;

        // issue batch(P+1) = W(s0+2), W(s1+2) into bufs (s0+2)&3, (s1+2)&3
        #pragma unroll
        for (int d2 = 2; d2 < 4; ++d2) {
            const int sp = s0 + d2;
            if (sp < 36) {
                const u16* src = wsrc_base + (sp << 12);
                u16* dst = wdst_base + ((sp & 3) << 12);
                gload16(src, dst);
                gload16(src + 512, dst + 512);
            }
        }

        // ================= step s0 (buf s0&3) =================
        {
            const int t = s0 % 9, kh = t / 3, kw = t - kh * 3;
            bf16x8 a[4], b[4];
            #pragma unroll
            for (int fi = 0; fi < 4; ++fi) {
                const u16* p = s_in + (a_base[fi] + kh * 18 + kw) * AS + (l4 << 3);
                a[fi] = __builtin_bit_cast(bf16x8, *(const short8*)p);
            }
            const u16* rb = &s_w[s0 & 3][0];
            #pragma unroll
            for (int nj = 0; nj < 4; ++nj)
                b[nj] = __builtin_bit_cast(bf16x8, *(const short8*)(rb + b_base[nj]));
            #pragma unroll
            for (int fi = 0; fi < 4; ++fi)
                #pragma unroll
                for (int nj = 0; nj < 4; ++nj)
                    acc[fi][nj] = __builtin_amdgcn_mfma_f32_16x16x32_bf16(
                        a[fi], b[nj], acc[fi][nj], 0, 0, 0);
        }

        // -------- mid-phase q-restage (s0 ends q, s1 starts q+1) --------
        if (s0 % 9 == 8) {
            const int qn = s0 / 9 + 1;
            asm volatile("s_waitcnt lgkmcnt(0)" ::: "memory");
            __builtin_amdgcn_s_barrier();       // all waves done reading q
            #pragma unroll
            for (int r2 = 0; r2 < 3; ++r2) {
                int g = tid + (r2 << 8);
                if (g < 720) {
                    int px = g >> 2, c8 = (g & 3) << 3;
                    int hh = px / 18, ww2 = px - hh * 18;
                    int gh = h0 + hh - 1, gw = w0 + ww2 - 1;
                    uint4 v = make_uint4(0, 0, 0, 0);
                    if ((unsigned)gh < 112u && (unsigned)gw < 112u)
                        v = *(const uint4*)(in_n + ((size_t)(gh * 112 + gw) << 7)
                                            + (qn << 5) + c8);
                    *(uint4*)(s_in + px * AS + c8) = v;
                }
            }
            asm volatile("s_waitcnt lgkmcnt(0)" ::: "memory");
            __builtin_amdgcn_s_barrier();       // new A visible
            __builtin_amdgcn_sched_barrier(0);
        }

        // ================= step s1 (buf s1&3) =================
        {
            const int t = s1 % 9, kh = t / 3, kw = t - kh * 3;
            bf16x8 a[4], b[4];
            #pragma unroll
            for (int fi = 0; fi < 4; ++fi) {
                const u16* p = s_in + (a_base[fi] + kh * 18 + kw) * AS + (l4 << 3);
                a[fi] = __builtin_bit_cast(bf16x8, *(const short8*)p);
            }
            const u16* rb = &s_w[s1 & 3][0];
            #pragma unroll
            for (int nj = 0; nj < 4; ++nj)
                b[nj] = __builtin_bit_cast(bf16x8, *(const short8*)(rb + b_base[nj]));
            #pragma unroll
            for (int fi = 0; fi < 4; ++fi)
                #pragma unroll
                for (int nj = 0; nj < 4; ++nj)
                    acc[fi][nj] = __builtin_amdgcn_mfma_f32_16x16x32_bf16(
                        a[fi], b[nj], acc[fi][nj], 0, 0, 0);
        }

        // ---- end of phase: own batch(P+1) landed, then block-wide sync ----
        asm volatile("s_waitcnt vmcnt(0)" ::: "memory");
        __builtin_amdgcn_s_barrier();
        __builtin_amdgcn_sched_barrier(0);

        // -------- phase-boundary q-restage (after s1 ends q) --------
        if (s1 % 9 == 8 && s1 != 35) {
            const int qn = s1 / 9 + 1;
            #pragma unroll
            for (int r2 = 0; r2 < 3; ++r2) {
                int g = tid + (r2 << 8);
                if (g < 720) {
                    int px = g >> 2, c8 = (g & 3) << 3;
                    int hh = px / 18, ww2 = px - hh * 18;
                    int gh = h0 + hh - 1, gw = w0 + ww2 - 1;
                    uint4 v = make_uint4(0, 0, 0, 0);
                    if ((unsigned)gh < 112u && (unsigned)gw < 112u)
                        v = *(const uint4*)(in_n + ((size_t)(gh * 112 + gw) << 7)
                                            + (qn << 5) + c8);
                    *(uint4*)(s_in + px * AS + c8) = v;
                }
            }
            asm volatile("s_waitcnt lgkmcnt(0)" ::: "memory");
            __builtin_amdgcn_s_barrier();
            __builtin_amdgcn_sched_barrier(0);
        }
    }

    // ---- epilogue: bias + relu, optional bf16 NHWC stores, fused pooling ----
    // D layout: col = lane&15 (cout), row = l4*4 + j (pixel-within-16)
    float bv[4], ps[4];
    #pragma unroll
    for (int nj = 0; nj < 4; ++nj) { bv[nj] = bias[wn * 64 + nj * 16 + l15]; ps[nj] = 0.f; }
    u16* out_n = outp + ((size_t)n * HW << 7);
    #pragma unroll
    for (int fi = 0; fi < 4; ++fi) {
        int h = h0 + wm * 4 + fi;
        #pragma unroll
        for (int j = 0; j < 4; ++j) {
            int w = w0 + (l4 << 2) + j;
            u16* pr = out_n + ((size_t)(h * 112 + w) << 7);
            #pragma unroll
            for (int nj = 0; nj < 4; ++nj) {
                float v = fmaxf(acc[fi][nj][j] + bv[nj], 0.f);
                ps[nj] += v;
                if (STORE) pr[wn * 64 + nj * 16 + l15] = f2bf(v);
            }
        }
    }
    #pragma unroll
    for (int nj = 0; nj < 4; ++nj) {
        ps[nj] += __shfl_xor(ps[nj], 16, 64);
        ps[nj] += __shfl_xor(ps[nj], 32, 64);
    }
    __syncthreads();    // all s_in reads long done; reuse as pool buffer
    if (l4 == 0) {
        #pragma unroll
        for (int nj = 0; nj < 4; ++nj)
            s_pool[wm * 128 + wn * 64 + nj * 16 + l15] = ps[nj];
    }
    __syncthreads();
    if (tid < 128)
        partial[((size_t)n * NTILE + tile) * 128 + tid] = s_pool[tid] + s_pool[128 + tid];
}

// ---------------- per-(depth,sample): reduce partials + 100 dot-128 ----------------
__global__ __launch_bounds__(128) void logits_k(
    const float* __restrict__ partial,  // [4][16][98][128]
    const float* __restrict__ cw,       // [4][100][128]
    const float* __restrict__ cb,       // [4][100]
    float* __restrict__ lg)             // [4][16][100]
{
    const int i = blockIdx.x, n = blockIdx.y;
    const int tid = threadIdx.x;
    __shared__ float pool[128];
    const float* pp = partial + ((size_t)(i * NB + n) * NTILE) * 128;
    float s = 0.f;
    for (int t = 0; t < NTILE; ++t) s += pp[t * 128 + tid];
    pool[tid] = s * (1.f / HW);
    __syncthreads();
    if (tid < NCLS) {
        const float* wp = cw + ((size_t)i * NCLS + tid) * CCH;
        float a = cb[i * NCLS + tid];
        #pragma unroll
        for (int c = 0; c < CCH; c += 4) {
            float4 w4 = *(const float4*)(wp + c);
            a += pool[c] * w4.x + pool[c + 1] * w4.y
               + pool[c + 2] * w4.z + pool[c + 3] * w4.w;
        }
        lg[(i * NB + n) * NCLS + tid] = a;
    }
}

// ---------------- early-exit selection ----------------
__global__ __launch_bounds__(256) void select_k(
    const float* __restrict__ lg,   // [4][16][100]
    float* __restrict__ out)        // [16][100]
{
    __shared__ float slg[4 * NB * NCLS];
    __shared__ int chosen[NB];
    const int tid = threadIdx.x;
    for (int e = tid; e < 4 * NB * NCLS; e += 256) slg[e] = lg[e];
    __syncthreads();
    if (tid < NB) {
        int n = tid, ch = 3;
        for (int i = 0; i < 3; i++) {
            const float* row = &slg[(i * NB + n) * NCLS];
            float m = -1e30f;
            for (int j = 0; j < NCLS; j++) m = fmaxf(m, row[j]);
            float se = 0.f;
            for (int j = 0; j < NCLS; j++) se += expf(row[j] - m);
            if (1.f / se >= 0.9f) { ch = i; break; }
        }
        chosen[n] = ch;
    }
    __syncthreads();
    for (int e = tid; e < NB * NCLS; e += 256) {
        int n = e / NCLS, j = e % NCLS;
        out[e] = slg[(chosen[n] * NB + n) * NCLS + j];
    }
}

extern "C" void kernel_launch(void* const* d_in, const int* in_sizes, int n_in,
                              void* d_out, int out_size, void* d_ws, size_t ws_size,
                              hipStream_t stream) {
    const float* x       = (const float*)d_in[0];
    const float* init_w  = (const float*)d_in[1];
    const float* init_b  = (const float*)d_in[2];
    const float* block_w = (const float*)d_in[3];
    const float* block_b = (const float*)d_in[4];
    const float* cls_w   = (const float*)d_in[5];
    const float* cls_b   = (const float*)d_in[6];
    float* out = (float*)d_out;

    char* ws = (char*)d_ws;
    u16* fA        = (u16*)ws;                      // 51,380,224 B
    u16* fB        = (u16*)(ws + 51380224);         // 51,380,224 B
    u16* wbs       = (u16*)(ws + 102760448);        //  1,179,648 B
    float* partial = (float*)(ws + 103940096);      // 4*16*98*128*4 = 3,211,264 B
    float* lgbuf   = (float*)(ws + 107151360);      // 4*16*100*4 = 25,600 B

    convert_w<<<2304, 256, 0, stream>>>(block_w, wbs);
    conv_init<<<dim3(49, 4, NB), 256, 0, stream>>>(
        x, init_w + 2 * 128 * 27, init_b + 2 * 128, fA);

    u16* cur = fA;
    u16* nxt = fB;
    for (int i = 0; i < 4; ++i) {
        if (i < 3)
            conv_mfma<true><<<dim3(NTILE, NB), 256, 0, stream>>>(
                cur, wbs + (size_t)i * 147456, block_b + (i * 3 + 2) * 128, nxt,
                partial + (size_t)i * NB * NTILE * 128);
        else
            conv_mfma<false><<<dim3(NTILE, NB), 256, 0, stream>>>(
                cur, wbs + (size_t)i * 147456, block_b + (i * 3 + 2) * 128, nxt,
                partial + (size_t)i * NB * NTILE * 128);
        u16* t = cur; cur = nxt; nxt = t;
    }

    logits_k<<<dim3(4, NB), 128, 0, stream>>>(partial, cls_w, cls_b, lgbuf);
    select_k<<<1, 256, 0, stream>>>(lgbuf, out);
}